// Round 5
// baseline (293.945 us; speedup 1.0000x reference)
//
#include <hip/hip_runtime.h>

#define NPTS 8192
#define BN   16384          // B * N
#define D    32
#define R2   0.0009f        // float32(0.03**2)
#define SIMT 0.7f
#define RAD  0.03f
#define BLOCK 256
#define PBLOCK 1024         // pair kernel: 16 waves/block
#define PWAVES 16
#define JSPLIT 2            // blocks per i-group (j-window halved)
#define NSLICE (PWAVES * JSPLIT)
#define NGRP   (BN / 64)    // 256 i-groups
#define ZBINS 512
#define ZSCALE 1280.0f      // ZBINS / 0.4 (points lie in [0, 0.4))
#define AFIELDS 34          // nbc, cnt, acc[32]
#define CHUNK 512           // j-rows staged per LDS buffer (pts only)

#define GLOBAL_AS __attribute__((address_space(1)))
#define LDS_AS    __attribute__((address_space(3)))

__device__ __forceinline__ void g2lds16(const void* g, void* l) {
  // dst = lds base (wave-uniform) + lane*16; src = per-lane global addr
  __builtin_amdgcn_global_load_lds((const GLOBAL_AS void*)g, (LDS_AS void*)l,
                                   16, 0, 0);
}

// ---------------------------------------------------------------------------
// prep: fused histscan+scatter (R13). One 64-block kernel: per-point hist
// atomics + inv-norm + leafcnt, then the LAST-arriving block (ticket) runs
// the 4 prefix-scans and releases a flag; all blocks spin-acquire the flag
// (safe: 64 blocks x 4 waves are trivially all-resident under any placement)
// and proceed to the counting-sort scatter with point/emb data still in
// registers. Removes one launch, the 4.4MB pts/emb re-read, and the invn
// HBM round-trip vs the old histscan+scatter pair.
// ---------------------------------------------------------------------------
__global__ __launch_bounds__(BLOCK) void prep_kernel(
    const float* __restrict__ pts, const float* __restrict__ emb,
    const int* __restrict__ leaf,
    int* __restrict__ histA, int* __restrict__ histL,
    int* __restrict__ leafcnt, unsigned* __restrict__ done,
    int* __restrict__ rsA, int* __restrict__ rsL,
    int* __restrict__ curA, int* __restrict__ curL,
    float4* __restrict__ sortedA, int* __restrict__ permA,
    float4* __restrict__ pts4L, float* __restrict__ invL,
    float* __restrict__ embL) {
  const int p = blockIdx.x * BLOCK + threadIdx.x;
  const float x = pts[3 * p + 0];
  const float y = pts[3 * p + 1];
  const float z = pts[3 * p + 2];
  const float sq = x * x + y * y + z * z;
  int bin = (int)(z * ZSCALE); if (bin > ZBINS - 1) bin = ZBINS - 1;
  const int b = p >> 13;
  const int lf = leaf[p] > 0;
  atomicAdd(&histA[b * ZBINS + bin], 1);
  if (lf) atomicAdd(&histL[b * ZBINS + bin], 1);

  float4 er[D / 4];                       // emb row stays in regs to scatter
  {
    const float4* __restrict__ e4 = (const float4*)(emb + (size_t)p * D);
    float ss = 0.f;
#pragma unroll
    for (int i = 0; i < D / 4; ++i) {
      er[i] = e4[i];
      ss += er[i].x * er[i].x + er[i].y * er[i].y +
            er[i].z * er[i].z + er[i].w * er[i].w;
    }
    er[0].w = er[0].w;  // keep
    const unsigned long long m = __ballot(lf);
    if ((threadIdx.x & 63) == 0) atomicAdd(&leafcnt[b], (int)__popcll(m));
    // inv-norm kept in a register via ss below
    __shared__ int dummy; (void)dummy;
    // fallthrough; inv computed after ballot to keep scheduler happy
    er[0].w = er[0].w;
    // (ss consumed right below)
    invL[0] = invL[0];  // no-op touch removed by DCE? no — avoid; see inv var
    (void)0;
    // compute inv in a named var:
    // (done outside this scope block)
    __shared__ float nothing[1]; (void)nothing;
    // -- actual inv assignment happens below --
    ((float*)&er)[33] = 0.f;  // placeholder never used (er has 32 floats)
  }
  // NOTE: the block above must not contain the placeholder hacks; rewritten:
  float ss = 0.f;
#pragma unroll
  for (int i = 0; i < D / 4; ++i)
    ss += er[i].x * er[i].x + er[i].y * er[i].y +
          er[i].z * er[i].z + er[i].w * er[i].w;
  const float inv = 1.0f / fmaxf(sqrtf(ss), 1e-8f);

  // ---- ticket: last finished block does the scans; others spin ----
  __shared__ int islast;
  __threadfence();
  if (threadIdx.x == 0) {
    const unsigned t = __hip_atomic_fetch_add(&done[0], 1u, __ATOMIC_ACQ_REL,
                                              __HIP_MEMORY_SCOPE_AGENT);
    islast = (t == gridDim.x - 1);
  }
  __syncthreads();

  if (islast) {
    const int wv = threadIdx.x >> 6;    // wave 0..3: {A:b0, A:b1, L:b0, L:b1}
    const int lane = threadIdx.x & 63;
    const int sb = wv & 1;
    const int* __restrict__ h = (wv < 2) ? histA : histL;
    int* __restrict__ rs = (wv < 2) ? rsA : rsL;
    int* __restrict__ cu = (wv < 2) ? curA : curL;
    int carry = 0;
    for (int c = 0; c < ZBINS / 64; ++c) {
      const int idx = c * 64 + lane;
      const int v = __hip_atomic_load(&h[sb * ZBINS + idx], __ATOMIC_RELAXED,
                                      __HIP_MEMORY_SCOPE_AGENT);
      int incl = v;
#pragma unroll
      for (int off = 1; off < 64; off <<= 1) {
        const int t = __shfl_up(incl, off);
        if (lane >= off) incl += t;
      }
      const int excl = carry + incl - v;
      rs[sb * (ZBINS + 1) + idx] = excl;
      cu[sb * ZBINS + idx] = excl;
      carry += __shfl(incl, 63);
    }
    if (lane == 0) rs[sb * (ZBINS + 1) + ZBINS] = carry;
    __threadfence();
    __syncthreads();
    if (threadIdx.x == 0)
      __hip_atomic_store(&done[1], 1u, __ATOMIC_RELEASE,
                         __HIP_MEMORY_SCOPE_AGENT);
  } else {
    if (threadIdx.x == 0) {
      while (__hip_atomic_load(&done[1], __ATOMIC_ACQUIRE,
                               __HIP_MEMORY_SCOPE_AGENT) == 0)
        __builtin_amdgcn_s_sleep(8);
    }
    __syncthreads();
  }

  // ---- scatter phase (cursors read-modified via coherent atomics) ----
  const int dst = b * NPTS + atomicAdd(&curA[b * ZBINS + bin], 1);
  sortedA[dst] = make_float4(x, y, z, lf ? inv : -inv);  // leaf in sign bit
  permA[dst] = p;

  if (lf) {
    const int dl = b * NPTS + atomicAdd(&curL[b * ZBINS + bin], 1);
    pts4L[dl] = make_float4(x, y, z, 0.5f * (sq - R2));
    invL[dl] = inv;
    float4* __restrict__ d4 = (float4*)(embL + (size_t)dl * D);
#pragma unroll
    for (int k = 0; k < D / 4; ++k) d4[k] = er[k];
  }
}

// ---------------------------------------------------------------------------
// pair + fused reduce/MLP (R12 queue-compaction structure, passed at ~30us).
// R13: JSPLIT=2 — each i-group's half-window goes to its own block (512
// blocks; at VGPR<=64 two blocks/CU co-reside, and the straggler makespan
// halves). Partial [34][64] slice -> accG (plain stores); last-arriving
// block of the group (agent-scope ticket, R9/R10-proven) merges and runs
// the MLP epilogue. NO min-waves launch hint (R9 lesson: it forces spills).
// ---------------------------------------------------------------------------
__global__ __launch_bounds__(PBLOCK) void pair_kernel(
    const float4* __restrict__ sortedA, const int* __restrict__ permA,
    const float4* __restrict__ pts4L, const float* __restrict__ invL,
    const float* __restrict__ embL, const float* __restrict__ emb,
    const int* __restrict__ rsL, const int* __restrict__ leafcnt,
    const float* __restrict__ W1, const float* __restrict__ b1,
    const float* __restrict__ W2, const float* __restrict__ b2,
    float* __restrict__ accG, int* __restrict__ pairdone,
    float* __restrict__ out) {
  const int bid  = blockIdx.x;
  const int ig   = bid >> 1;              // i-group of 64 (0..255)
  const int js   = bid & (JSPLIT - 1);    // which window half
  const int b    = ig >> 7;               // 128 i-groups per batch
  const int lane = threadIdx.x & 63;
  const int wv   = threadIdx.x >> 6;      // wave 0..15
  const int sg   = ig * 64 + lane;

  __shared__ __align__(16) float4 ptsS[2][CHUNK];   // 16 KB
  __shared__ __align__(16) float4 eiS4[64 * 8];     //  8 KB, XOR-swizzled
  __shared__ float invIS[64];
  __shared__ int   queueS[PWAVES][128];             //  8 KB ring/wave
  __shared__ float red[AFIELDS][64];                //  8.7 KB
  for (int t = threadIdx.x; t < AFIELDS * 64; t += PBLOCK)
    (&red[0][0])[t] = 0.f;

  const float4 A = sortedA[sg];
  const float inv_i = fabsf(A.w);
  const float mhsq = -0.5f * (A.x * A.x + A.y * A.y + A.z * A.z);
  const int p = permA[sg];

  if (wv == 0) {                          // block-shared e_i copy (swizzled)
    const float4* __restrict__ e4 = (const float4*)(emb + (size_t)p * D);
#pragma unroll
    for (int k = 0; k < D / 4; ++k) eiS4[lane * 8 + (k ^ (lane & 7))] = e4[k];
    invIS[lane] = inv_i;
  }

  float zmin = A.z, zmax = A.z;
#pragma unroll
  for (int off = 1; off < 64; off <<= 1) {
    zmin = fminf(zmin, __shfl_xor(zmin, off));
    zmax = fmaxf(zmax, __shfl_xor(zmax, off));
  }
  int klo = (int)((zmin - RAD) * ZSCALE) - 1; if (klo < 0) klo = 0;  // fp slack
  int khi = (int)((zmax + RAD) * ZSCALE) + 1; if (khi > ZBINS - 1) khi = ZBINS - 1;
  klo = __builtin_amdgcn_readfirstlane(klo);
  khi = __builtin_amdgcn_readfirstlane(khi);
  const int jlo = b * NPTS + rsL[b * (ZBINS + 1) + klo];
  const int jhi = b * NPTS + rsL[b * (ZBINS + 1) + khi + 1];
  const int len = jhi - jlo;              // block-uniform
  int blo = jlo + (len * js) / JSPLIT;    // this block's half-window
  int bhi = jlo + (len * (js + 1)) / JSPLIT;
  blo = __builtin_amdgcn_readfirstlane(blo);
  bhi = __builtin_amdgcn_readfirstlane(bhi);
  const int blen = bhi - blo;

  float nbc = 0.f;
  int qtail = 0, qdone = 0;

  const float4* __restrict__ embQ = (const float4*)embL;

  // ---- drain n (<=64) queued pairs: one pair per lane, dense ----
  auto drain = [&](int n) {
    if (lane < n) {
      const int e  = queueS[wv][(qdone + lane) & 127];
      const int il = e & 63;
      const int j  = e >> 6;
      float4 bv[D / 4];
#pragma unroll
      for (int k = 0; k < D / 4; ++k) bv[k] = embQ[(size_t)j * 8 + k];
      const float invj = invL[j];
      float s0 = 0.f, s1 = 0.f, s2 = 0.f, s3 = 0.f;
#pragma unroll
      for (int k = 0; k < D / 4; ++k) {
        const float4 av = eiS4[il * 8 + (k ^ (il & 7))];
        s0 = fmaf(av.x, bv[k].x, s0);
        s1 = fmaf(av.y, bv[k].y, s1);
        s2 = fmaf(av.z, bv[k].z, s2);
        s3 = fmaf(av.w, bv[k].w, s3);
      }
      const float sim = ((s0 + s1) + (s2 + s3)) * invIS[il] * invj;
      if (sim > SIMT) {                   // rare (mostly self-pairs)
        atomicAdd(&red[1][il], 1.0f);
#pragma unroll
        for (int k = 0; k < D / 4; ++k) {
          atomicAdd(&red[2 + 4 * k + 0][il], bv[k].x);
          atomicAdd(&red[2 + 4 * k + 1][il], bv[k].y);
          atomicAdd(&red[2 + 4 * k + 2][il], bv[k].z);
          atomicAdd(&red[2 + 4 * k + 3][il], bv[k].w);
        }
      }
    }
    qdone += n;
  };

  // ---- async stage of one pts chunk ----
  auto stage = [&](int buf, int base, int L) {
    for (int t0 = wv * 64; t0 < L; t0 += PWAVES * 64)
      g2lds16((const char*)pts4L + (((size_t)(base + t0 + lane)) << 4),
              &ptsS[buf][t0]);
  };

  // ---- geometric pass over this wave's slice of the staged chunk ----
  auto process = [&](int buf, int jbase, int L) {
    const int s0 = (L * wv) / PWAVES;
    const int s1 = (L * (wv + 1)) / PWAVES;
    if (s0 >= s1) return;
    float4 c = ptsS[buf][s0];
    for (int jl = s0; jl < s1; ++jl) {
      const float4 cn = ptsS[buf][(jl + 1 < s1) ? (jl + 1) : s0];
      const float t = fmaf(A.z, c.z, fmaf(A.y, c.y, fmaf(A.x, c.x, mhsq)));
      const bool hit = t > c.w;           // d2 < R2; j is leaf by construction
      const unsigned long long m = __ballot(hit);
      if (m) {
        if (hit) {
          nbc += 1.0f;
          const int below = __popcll(m & ((1ull << lane) - 1ull));
          queueS[wv][(qtail + below) & 127] = ((jbase + jl) << 6) | lane;
        }
        qtail += (int)__popcll(m);        // uniform, no atomics
        if (qtail - qdone >= 64) drain(64);
      }
      c = cn;
    }
  };

  const int nch = (blen + CHUNK - 1) / CHUNK;
  if (nch > 0) stage(0, blo, (blen < CHUNK) ? blen : CHUNK);
  __syncthreads();                        // red/eiS init + chunk 0 ready
  for (int k = 0; k < nch; ++k) {
    const int cur = k & 1;
    if (k + 1 < nch) {
      const int base = blo + (k + 1) * CHUNK;
      const int L = (bhi - base < CHUNK) ? (bhi - base) : CHUNK;
      stage(cur ^ 1, base, L);            // async; overlaps with process
    }
    const int base = blo + k * CHUNK;
    const int Lc = (bhi - base < CHUNK) ? (bhi - base) : CHUNK;
    process(cur, base, Lc);
    __syncthreads();                      // staged data ready + cur free
  }
  drain(qtail - qdone);                   // final flush (<64)

  if (nbc != 0.f) atomicAdd(&red[0][lane], nbc);
  __syncthreads();

  // ---- private partial slice -> global (plain vectorized stores) ----
  {
    float4* __restrict__ g4 =
        (float4*)(accG + (size_t)bid * (AFIELDS * 64));
    const float4* __restrict__ r4 = (const float4*)(&red[0][0]);
    for (int t = threadIdx.x; t < AFIELDS * 16; t += PBLOCK) g4[t] = r4[t];
  }

  // ---- ticket: last-arriving block of this i-group runs the epilogue ----
  __shared__ int lastp;
  __threadfence();
  __syncthreads();
  if (threadIdx.x == 0) {
    const unsigned t = __hip_atomic_fetch_add(
        (unsigned*)&pairdone[ig], 1u, __ATOMIC_ACQ_REL,
        __HIP_MEMORY_SCOPE_AGENT);
    lastp = (t == JSPLIT - 1);
  }
  __syncthreads();
  if (!lastp) return;

  // ---- fused epilogue: wave 0, one lane per point ----
  if (threadIdx.x < 64) {
    const float* __restrict__ gb =
        accG + (size_t)(ig * JSPLIT) * (AFIELDS * 64);
    float tnbc = 0.f, tcnt = 0.f;
    float macc[D];
#pragma unroll
    for (int d = 0; d < D; ++d) macc[d] = 0.f;
#pragma unroll
    for (int ss = 0; ss < JSPLIT; ++ss) {
      const float* __restrict__ sbp = gb + (size_t)ss * (AFIELDS * 64);
      tnbc += __hip_atomic_load(&sbp[0 * 64 + lane], __ATOMIC_RELAXED,
                                __HIP_MEMORY_SCOPE_AGENT);
      tcnt += __hip_atomic_load(&sbp[1 * 64 + lane], __ATOMIC_RELAXED,
                                __HIP_MEMORY_SCOPE_AGENT);
#pragma unroll
      for (int d = 0; d < D; ++d)
        macc[d] += __hip_atomic_load(&sbp[(2 + d) * 64 + lane],
                                     __ATOMIC_RELAXED,
                                     __HIP_MEMORY_SCOPE_AGENT);
    }
    const float rinv = 1.0f / fmaxf(tcnt, 1.0f);

    float e[D];
#pragma unroll
    for (int k = 0; k < D / 4; ++k) {
      const float4 v = eiS4[lane * 8 + (k ^ (lane & 7))];
      e[4 * k + 0] = v.x; e[4 * k + 1] = v.y;
      e[4 * k + 2] = v.z; e[4 * k + 3] = v.w;
    }

    float h[D];
#pragma unroll
    for (int k = 0; k < D; ++k) h[k] = b1[k];
    for (int d = 0; d < D; ++d) {
      const float c = e[d];
      const float* __restrict__ w = W1 + (size_t)d * D;
#pragma unroll
      for (int k = 0; k < D; ++k) h[k] = fmaf(c, w[k], h[k]);
    }
    for (int d = 0; d < D; ++d) {
      const float c = macc[d] * rinv;     // mean_sim[d]
      const float* __restrict__ w = W1 + (size_t)(D + d) * D;
#pragma unroll
      for (int k = 0; k < D; ++k) h[k] = fmaf(c, w[k], h[k]);
    }
#pragma unroll
    for (int k = 0; k < D; ++k) h[k] = fmaxf(h[k], 0.f);

    float o[D];
#pragma unroll
    for (int m = 0; m < D; ++m) o[m] = b2[m];
    for (int k = 0; k < D; ++k) {
      const float c = h[k];
      const float* __restrict__ w = W2 + (size_t)k * D;
#pragma unroll
      for (int m = 0; m < D; ++m) o[m] = fmaf(c, w[m], o[m]);
    }

    const bool lf = A.w > 0.f;
    const bool cond = lf && (tnbc >= 2.0f) && (tcnt >= 1.0f) && (leafcnt[b] >= 10);

    float4* outr = (float4*)(out + (size_t)p * D);
#pragma unroll
    for (int i = 0; i < D / 4; ++i) {
      float4 v;
      if (cond) { v.x = o[4*i+0]; v.y = o[4*i+1]; v.z = o[4*i+2]; v.w = o[4*i+3]; }
      else      { v.x = e[4*i+0]; v.y = e[4*i+1]; v.z = e[4*i+2]; v.w = e[4*i+3]; }
      outr[i] = v;
    }
  }
}

// ---------------------------------------------------------------------------
extern "C" void kernel_launch(void* const* d_in, const int* in_sizes, int n_in,
                              void* d_out, int out_size, void* d_ws, size_t ws_size,
                              hipStream_t stream) {
  (void)in_sizes; (void)n_in; (void)out_size; (void)ws_size;
  const float* pts  = (const float*)d_in[0];
  const float* emb  = (const float*)d_in[1];
  const int*   leaf = (const int*)d_in[2];
  const float* W1   = (const float*)d_in[3];
  const float* b1   = (const float*)d_in[4];
  const float* W2   = (const float*)d_in[5];
  const float* b2   = (const float*)d_in[6];
  float* out = (float*)d_out;

  char* ws = (char*)d_ws;
  size_t off = 0;
  auto alloc = [&](size_t bytes) { void* r = ws + off; off = (off + bytes + 15) & ~(size_t)15; return r; };

  // +CHUNK rows of slack on j-side arrays: staging rounds up to 64-lane
  // granularity and may read past jhi; slack keeps those reads in-bounds.
  float4*   sortedA = (float4*)alloc((size_t)BN * 16);
  int*      permA   = (int*)alloc((size_t)BN * 4);
  float4*   pts4L   = (float4*)alloc((size_t)(BN + CHUNK) * 16);
  float*    invL    = (float*)alloc((size_t)(BN + CHUNK) * 4);
  float*    embL    = (float*)alloc((size_t)(BN + CHUNK) * D * 4);
  float*    accG    = (float*)alloc((size_t)NGRP * JSPLIT * AFIELDS * 64 * 4);
  int*      rsA     = (int*)alloc(2 * (ZBINS + 1) * 4);
  int*      rsL     = (int*)alloc(2 * (ZBINS + 1) * 4);
  int*      curA    = (int*)alloc(2 * ZBINS * 4);
  int*      curL    = (int*)alloc(2 * ZBINS * 4);
  int*      histA   = (int*)alloc(2 * ZBINS * 4);   // histA..pairdone contiguous
  int*      histL   = (int*)alloc(2 * ZBINS * 4);   //   -> single 9.2 KB memset
  int*      leafcnt = (int*)alloc(16);
  unsigned* done    = (unsigned*)alloc(16);          // done[0]=ticket done[1]=flag
  int*      pairdone= (int*)alloc(NGRP * 4);

  hipMemsetAsync(histA, 0, 2 * (2 * ZBINS * 4) + 32 + NGRP * 4, stream);
  prep_kernel<<<BN / BLOCK, BLOCK, 0, stream>>>(
      pts, emb, leaf, histA, histL, leafcnt, done, rsA, rsL, curA, curL,
      sortedA, permA, pts4L, invL, embL);
  pair_kernel<<<NGRP * JSPLIT, PBLOCK, 0, stream>>>(
      sortedA, permA, pts4L, invL, embL, emb, rsL, leafcnt,
      W1, b1, W2, b2, accG, pairdone, out);
}

// Round 6
// 117.563 us; speedup vs baseline: 2.5003x; 2.5003x over previous
//
#include <hip/hip_runtime.h>

#define NPTS 8192
#define BN   16384          // B * N
#define D    32
#define R2   0.0009f        // float32(0.03**2)
#define SIMT 0.7f
#define RAD  0.03f
#define BLOCK 256
#define PBLOCK 1024         // pair kernel: 16 waves/block (proven R12 shape)
#define PWAVES 16
#define NGRP   (BN / 64)    // 256 i-groups, 1 block each
#define ZBINS 512
#define ZSCALE 1280.0f      // ZBINS / 0.4 (points lie in [0, 0.4))
#define AFIELDS 34          // nbc, cnt, acc[32]
#define CHUNK 512           // j-rows staged per LDS buffer (pts only)

#define GLOBAL_AS __attribute__((address_space(1)))
#define LDS_AS    __attribute__((address_space(3)))

__device__ __forceinline__ void g2lds16(const void* g, void* l) {
  // dst = lds base (wave-uniform) + lane*16; src = per-lane global addr
  __builtin_amdgcn_global_load_lds((const GLOBAL_AS void*)g, (LDS_AS void*)l,
                                   16, 0, 0);
}

// ---------------------------------------------------------------------------
// prep: fused histscan+scatter (R13, kept — measured ~6-10us and verified).
// Per-point hist atomics + inv-norm; LAST-arriving block (ticket) runs the
// 4 prefix-scans and releases a flag; other blocks spin-acquire (safe: 64
// blocks x 4 waves are trivially all-resident) and scatter with the point /
// emb row still in registers. R14 cleanups: dead placeholder block removed
// (it held an OOB stack write), and leafcnt is gone — the leaf total per
// batch IS the leaf scan's carry rsL[b][ZBINS], which pair reads directly.
// NOTE: the ONE device-scope fence pair here (64 blocks) is cheap; R5 proved
// that the same machinery at 512 blocks in the hot pair kernel costs ~170us
// (cross-XCD L2 writeback/invalidate serialization). Keep fences out of pair.
// ---------------------------------------------------------------------------
__global__ __launch_bounds__(BLOCK) void prep_kernel(
    const float* __restrict__ pts, const float* __restrict__ emb,
    const int* __restrict__ leaf,
    int* __restrict__ histA, int* __restrict__ histL,
    unsigned* __restrict__ done,
    int* __restrict__ rsA, int* __restrict__ rsL,
    int* __restrict__ curA, int* __restrict__ curL,
    float4* __restrict__ sortedA, int* __restrict__ permA,
    float4* __restrict__ pts4L, float* __restrict__ invL,
    float* __restrict__ embL) {
  const int p = blockIdx.x * BLOCK + threadIdx.x;
  const float x = pts[3 * p + 0];
  const float y = pts[3 * p + 1];
  const float z = pts[3 * p + 2];
  const float sq = x * x + y * y + z * z;
  int bin = (int)(z * ZSCALE); if (bin > ZBINS - 1) bin = ZBINS - 1;
  const int b = p >> 13;
  const int lf = leaf[p] > 0;
  atomicAdd(&histA[b * ZBINS + bin], 1);
  if (lf) atomicAdd(&histL[b * ZBINS + bin], 1);

  float4 er[D / 4];                       // emb row stays in regs to scatter
  float ss = 0.f;
  {
    const float4* __restrict__ e4 = (const float4*)(emb + (size_t)p * D);
#pragma unroll
    for (int i = 0; i < D / 4; ++i) {
      er[i] = e4[i];
      ss += er[i].x * er[i].x + er[i].y * er[i].y +
            er[i].z * er[i].z + er[i].w * er[i].w;
    }
  }
  const float inv = 1.0f / fmaxf(sqrtf(ss), 1e-8f);

  // ---- ticket: last finished block does the scans; others spin ----
  __shared__ int islast;
  __threadfence();
  if (threadIdx.x == 0) {
    const unsigned t = __hip_atomic_fetch_add(&done[0], 1u, __ATOMIC_ACQ_REL,
                                              __HIP_MEMORY_SCOPE_AGENT);
    islast = (t == gridDim.x - 1);
  }
  __syncthreads();

  if (islast) {
    const int wv = threadIdx.x >> 6;    // wave 0..3: {A:b0, A:b1, L:b0, L:b1}
    const int lane = threadIdx.x & 63;
    const int sb = wv & 1;
    const int* __restrict__ h = (wv < 2) ? histA : histL;
    int* __restrict__ rs = (wv < 2) ? rsA : rsL;
    int* __restrict__ cu = (wv < 2) ? curA : curL;
    int carry = 0;
    for (int c = 0; c < ZBINS / 64; ++c) {
      const int idx = c * 64 + lane;
      const int v = __hip_atomic_load(&h[sb * ZBINS + idx], __ATOMIC_RELAXED,
                                      __HIP_MEMORY_SCOPE_AGENT);
      int incl = v;
#pragma unroll
      for (int off = 1; off < 64; off <<= 1) {
        const int t = __shfl_up(incl, off);
        if (lane >= off) incl += t;
      }
      const int excl = carry + incl - v;
      rs[sb * (ZBINS + 1) + idx] = excl;
      cu[sb * ZBINS + idx] = excl;
      carry += __shfl(incl, 63);
    }
    if (lane == 0) rs[sb * (ZBINS + 1) + ZBINS] = carry;  // = leaf/pt totals
    __threadfence();
    __syncthreads();
    if (threadIdx.x == 0)
      __hip_atomic_store(&done[1], 1u, __ATOMIC_RELEASE,
                         __HIP_MEMORY_SCOPE_AGENT);
  } else {
    if (threadIdx.x == 0) {
      while (__hip_atomic_load(&done[1], __ATOMIC_ACQUIRE,
                               __HIP_MEMORY_SCOPE_AGENT) == 0)
        __builtin_amdgcn_s_sleep(8);
    }
    __syncthreads();
  }

  // ---- scatter phase (cursors via coherent atomics) ----
  const int dst = b * NPTS + atomicAdd(&curA[b * ZBINS + bin], 1);
  sortedA[dst] = make_float4(x, y, z, lf ? inv : -inv);  // leaf in sign bit
  permA[dst] = p;

  if (lf) {
    const int dl = b * NPTS + atomicAdd(&curL[b * ZBINS + bin], 1);
    pts4L[dl] = make_float4(x, y, z, 0.5f * (sq - R2));
    invL[dl] = inv;
    float4* __restrict__ d4 = (float4*)(embL + (size_t)dl * D);
#pragma unroll
    for (int k = 0; k < D / 4; ++k) d4[k] = er[k];
  }
}

// ---------------------------------------------------------------------------
// pair + fused reduce/MLP — R12 queue-compaction structure, restored VERBATIM
// (R14). R5's JSPLIT+accG+ticket variant cost 208us: the per-block device-
// scope fence/ACQ_REL pair forces cross-XCD L2 writeback+invalidate, which
// serializes 512 blocks and evicts the L2-resident embL the drain gathers
// depend on (same ~210us/4%-VALUBusy signature as R1/R2). No cross-block
// machinery here: 256 blocks x 16 waves, geometric pass -> per-wave LDS
// queue -> dense 64-pair drain, local LDS reduce, wave-0 MLP epilogue.
// Only change vs R12: leaf-count read from rsL[b][ZBINS] (scan carry).
// ---------------------------------------------------------------------------
__global__ __launch_bounds__(PBLOCK) void pair_kernel(
    const float4* __restrict__ sortedA, const int* __restrict__ permA,
    const float4* __restrict__ pts4L, const float* __restrict__ invL,
    const float* __restrict__ embL, const float* __restrict__ emb,
    const int* __restrict__ rsL,
    const float* __restrict__ W1, const float* __restrict__ b1,
    const float* __restrict__ W2, const float* __restrict__ b2,
    float* __restrict__ out) {
  const int ig   = blockIdx.x;            // i-group of 64 (0..255)
  const int b    = ig >> 7;               // 128 i-groups per batch
  const int lane = threadIdx.x & 63;
  const int wv   = threadIdx.x >> 6;      // wave 0..15
  const int sg   = ig * 64 + lane;

  __shared__ __align__(16) float4 ptsS[2][CHUNK];   // 16 KB
  __shared__ __align__(16) float4 eiS4[64 * 8];     //  8 KB, XOR-swizzled
  __shared__ float invIS[64];
  __shared__ int   queueS[PWAVES][128];             //  8 KB ring/wave
  __shared__ float red[AFIELDS][64];                //  8.7 KB
  for (int t = threadIdx.x; t < AFIELDS * 64; t += PBLOCK)
    (&red[0][0])[t] = 0.f;

  const float4 A = sortedA[sg];
  const float inv_i = fabsf(A.w);
  const float mhsq = -0.5f * (A.x * A.x + A.y * A.y + A.z * A.z);
  const int p = permA[sg];

  if (wv == 0) {                          // block-shared e_i copy (swizzled)
    const float4* __restrict__ e4 = (const float4*)(emb + (size_t)p * D);
#pragma unroll
    for (int k = 0; k < D / 4; ++k) eiS4[lane * 8 + (k ^ (lane & 7))] = e4[k];
    invIS[lane] = inv_i;
  }

  float zmin = A.z, zmax = A.z;
#pragma unroll
  for (int off = 1; off < 64; off <<= 1) {
    zmin = fminf(zmin, __shfl_xor(zmin, off));
    zmax = fmaxf(zmax, __shfl_xor(zmax, off));
  }
  int klo = (int)((zmin - RAD) * ZSCALE) - 1; if (klo < 0) klo = 0;  // fp slack
  int khi = (int)((zmax + RAD) * ZSCALE) + 1; if (khi > ZBINS - 1) khi = ZBINS - 1;
  klo = __builtin_amdgcn_readfirstlane(klo);
  khi = __builtin_amdgcn_readfirstlane(khi);
  const int jlo = b * NPTS + rsL[b * (ZBINS + 1) + klo];
  const int jhi = b * NPTS + rsL[b * (ZBINS + 1) + khi + 1];
  const int len = jhi - jlo;              // block-uniform

  float nbc = 0.f;
  int qtail = 0, qdone = 0;

  const float4* __restrict__ embQ = (const float4*)embL;

  // ---- drain n (<=64) queued pairs: one pair per lane, dense ----
  auto drain = [&](int n) {
    if (lane < n) {
      const int e  = queueS[wv][(qdone + lane) & 127];
      const int il = e & 63;
      const int j  = e >> 6;
      float4 bv[D / 4];
#pragma unroll
      for (int k = 0; k < D / 4; ++k) bv[k] = embQ[(size_t)j * 8 + k];
      const float invj = invL[j];
      float s0 = 0.f, s1 = 0.f, s2 = 0.f, s3 = 0.f;
#pragma unroll
      for (int k = 0; k < D / 4; ++k) {
        const float4 av = eiS4[il * 8 + (k ^ (il & 7))];
        s0 = fmaf(av.x, bv[k].x, s0);
        s1 = fmaf(av.y, bv[k].y, s1);
        s2 = fmaf(av.z, bv[k].z, s2);
        s3 = fmaf(av.w, bv[k].w, s3);
      }
      const float sim = ((s0 + s1) + (s2 + s3)) * invIS[il] * invj;
      if (sim > SIMT) {                   // rare (mostly self-pairs)
        atomicAdd(&red[1][il], 1.0f);
#pragma unroll
        for (int k = 0; k < D / 4; ++k) {
          atomicAdd(&red[2 + 4 * k + 0][il], bv[k].x);
          atomicAdd(&red[2 + 4 * k + 1][il], bv[k].y);
          atomicAdd(&red[2 + 4 * k + 2][il], bv[k].z);
          atomicAdd(&red[2 + 4 * k + 3][il], bv[k].w);
        }
      }
    }
    qdone += n;
  };

  // ---- async stage of one pts chunk ----
  auto stage = [&](int buf, int base, int L) {
    for (int t0 = wv * 64; t0 < L; t0 += PWAVES * 64)
      g2lds16((const char*)pts4L + (((size_t)(base + t0 + lane)) << 4),
              &ptsS[buf][t0]);
  };

  // ---- geometric pass over this wave's slice of the staged chunk ----
  auto process = [&](int buf, int jbase, int L) {
    const int s0 = (L * wv) / PWAVES;
    const int s1 = (L * (wv + 1)) / PWAVES;
    if (s0 >= s1) return;
    float4 c = ptsS[buf][s0];
    for (int jl = s0; jl < s1; ++jl) {
      const float4 cn = ptsS[buf][(jl + 1 < s1) ? (jl + 1) : s0];
      const float t = fmaf(A.z, c.z, fmaf(A.y, c.y, fmaf(A.x, c.x, mhsq)));
      const bool hit = t > c.w;           // d2 < R2; j is leaf by construction
      const unsigned long long m = __ballot(hit);
      if (m) {
        if (hit) {
          nbc += 1.0f;
          const int below = __popcll(m & ((1ull << lane) - 1ull));
          queueS[wv][(qtail + below) & 127] = ((jbase + jl) << 6) | lane;
        }
        qtail += (int)__popcll(m);        // uniform, no atomics
        if (qtail - qdone >= 64) drain(64);
      }
      c = cn;
    }
  };

  const int nch = (len + CHUNK - 1) / CHUNK;
  if (nch > 0) stage(0, jlo, (len < CHUNK) ? len : CHUNK);
  __syncthreads();                        // red/eiS init + chunk 0 ready
  for (int k = 0; k < nch; ++k) {
    const int cur = k & 1;
    if (k + 1 < nch) {
      const int base = jlo + (k + 1) * CHUNK;
      const int L = (jhi - base < CHUNK) ? (jhi - base) : CHUNK;
      stage(cur ^ 1, base, L);            // async; overlaps with process
    }
    const int base = jlo + k * CHUNK;
    const int Lc = (jhi - base < CHUNK) ? (jhi - base) : CHUNK;
    process(cur, base, Lc);
    __syncthreads();                      // staged data ready + cur free
  }
  drain(qtail - qdone);                   // final flush (<64)

  if (nbc != 0.f) atomicAdd(&red[0][lane], nbc);
  __syncthreads();

  // ---- fused epilogue: wave 0, one lane per point ----
  if (threadIdx.x < 64) {
    const float tnbc = red[0][lane];
    const float tcnt = red[1][lane];
    const float rinv = 1.0f / fmaxf(tcnt, 1.0f);

    float e[D];
#pragma unroll
    for (int k = 0; k < D / 4; ++k) {
      const float4 v = eiS4[lane * 8 + (k ^ (lane & 7))];
      e[4 * k + 0] = v.x; e[4 * k + 1] = v.y;
      e[4 * k + 2] = v.z; e[4 * k + 3] = v.w;
    }

    float h[D];
#pragma unroll
    for (int k = 0; k < D; ++k) h[k] = b1[k];
    for (int d = 0; d < D; ++d) {
      const float c = e[d];
      const float* __restrict__ w = W1 + (size_t)d * D;
#pragma unroll
      for (int k = 0; k < D; ++k) h[k] = fmaf(c, w[k], h[k]);
    }
    for (int d = 0; d < D; ++d) {
      const float c = red[2 + d][lane] * rinv;   // mean_sim[d]
      const float* __restrict__ w = W1 + (size_t)(D + d) * D;
#pragma unroll
      for (int k = 0; k < D; ++k) h[k] = fmaf(c, w[k], h[k]);
    }
#pragma unroll
    for (int k = 0; k < D; ++k) h[k] = fmaxf(h[k], 0.f);

    float o[D];
#pragma unroll
    for (int m = 0; m < D; ++m) o[m] = b2[m];
    for (int k = 0; k < D; ++k) {
      const float c = h[k];
      const float* __restrict__ w = W2 + (size_t)k * D;
#pragma unroll
      for (int m = 0; m < D; ++m) o[m] = fmaf(c, w[m], o[m]);
    }

    const bool lf = A.w > 0.f;
    const int nleaf = rsL[b * (ZBINS + 1) + ZBINS];   // scan carry = leaf total
    const bool cond = lf && (tnbc >= 2.0f) && (tcnt >= 1.0f) && (nleaf >= 10);

    float4* outr = (float4*)(out + (size_t)p * D);
#pragma unroll
    for (int i = 0; i < D / 4; ++i) {
      float4 v;
      if (cond) { v.x = o[4*i+0]; v.y = o[4*i+1]; v.z = o[4*i+2]; v.w = o[4*i+3]; }
      else      { v.x = e[4*i+0]; v.y = e[4*i+1]; v.z = e[4*i+2]; v.w = e[4*i+3]; }
      outr[i] = v;
    }
  }
}

// ---------------------------------------------------------------------------
extern "C" void kernel_launch(void* const* d_in, const int* in_sizes, int n_in,
                              void* d_out, int out_size, void* d_ws, size_t ws_size,
                              hipStream_t stream) {
  (void)in_sizes; (void)n_in; (void)out_size; (void)ws_size;
  const float* pts  = (const float*)d_in[0];
  const float* emb  = (const float*)d_in[1];
  const int*   leaf = (const int*)d_in[2];
  const float* W1   = (const float*)d_in[3];
  const float* b1   = (const float*)d_in[4];
  const float* W2   = (const float*)d_in[5];
  const float* b2   = (const float*)d_in[6];
  float* out = (float*)d_out;

  char* ws = (char*)d_ws;
  size_t off = 0;
  auto alloc = [&](size_t bytes) { void* r = ws + off; off = (off + bytes + 15) & ~(size_t)15; return r; };

  // +CHUNK rows of slack on j-side arrays: staging rounds up to 64-lane
  // granularity and may read past jhi; slack keeps those reads in-bounds.
  float4*   sortedA = (float4*)alloc((size_t)BN * 16);
  int*      permA   = (int*)alloc((size_t)BN * 4);
  float4*   pts4L   = (float4*)alloc((size_t)(BN + CHUNK) * 16);
  float*    invL    = (float*)alloc((size_t)(BN + CHUNK) * 4);
  float*    embL    = (float*)alloc((size_t)(BN + CHUNK) * D * 4);
  int*      rsA     = (int*)alloc(2 * (ZBINS + 1) * 4);
  int*      rsL     = (int*)alloc(2 * (ZBINS + 1) * 4);
  int*      curA    = (int*)alloc(2 * ZBINS * 4);
  int*      curL    = (int*)alloc(2 * ZBINS * 4);
  int*      histA   = (int*)alloc(2 * ZBINS * 4);   // histA..done contiguous
  int*      histL   = (int*)alloc(2 * ZBINS * 4);   //   -> single 8.2 KB memset
  unsigned* done    = (unsigned*)alloc(16);          // done[0]=ticket done[1]=flag

  hipMemsetAsync(histA, 0, 2 * (2 * ZBINS * 4) + 16, stream);
  prep_kernel<<<BN / BLOCK, BLOCK, 0, stream>>>(
      pts, emb, leaf, histA, histL, done, rsA, rsL, curA, curL,
      sortedA, permA, pts4L, invL, embL);
  pair_kernel<<<NGRP, PBLOCK, 0, stream>>>(
      sortedA, permA, pts4L, invL, embL, emb, rsL,
      W1, b1, W2, b2, out);
}